// Round 1
// baseline (1022.428 us; speedup 1.0000x reference)
//
#include <hip/hip_runtime.h>

#define B 16
#define N 1024
#define F_IN 64
#define H 256
#define NEG -9e15f
#define ALPHA 0.2f

// ---------------------------------------------------------------------------
// adj [B,N,N] f32 -> bitmask [B*N][N/64] u64 (read adj once: 64MB -> 2MB)
__global__ void k_mask(const float* __restrict__ adj, unsigned long long* __restrict__ mask) {
    const int lane = threadIdx.x & 63;
    const int wave = blockIdx.x * (blockDim.x >> 6) + (threadIdx.x >> 6);
    const int nwaves = gridDim.x * (blockDim.x >> 6);
    const int words = B * N * (N / 64);
    for (int w = wave; w < words; w += nwaves) {
        float v = adj[w * 64 + lane];           // flat: ((b*N+i)*N + jw*64 + lane)
        unsigned long long m = __ballot(v > 0.f);
        if (lane == 0) mask[w] = m;
    }
}

// ---------------------------------------------------------------------------
// x[row, c] = sum_f nf[row, f] * W[f, c] + b[c]   (rows = B*N, F_IN=64, H=256)
#define EMB_ROWS 8
__global__ __launch_bounds__(256) void k_embed(const float* __restrict__ nf,
                                               const float* __restrict__ W,
                                               const float* __restrict__ bias,
                                               float* __restrict__ x) {
    __shared__ float nfs[F_IN][EMB_ROWS];
    const int row0 = blockIdx.x * EMB_ROWS;
    const int t = threadIdx.x;
    for (int idx = t; idx < EMB_ROWS * F_IN; idx += 256) {
        int r = idx >> 6, f = idx & 63;
        nfs[f][r] = nf[(row0 + r) * F_IN + f];
    }
    __syncthreads();
    const int c = t;
    float acc[EMB_ROWS];
    float bv = bias[c];
#pragma unroll
    for (int r = 0; r < EMB_ROWS; r++) acc[r] = bv;
    for (int f = 0; f < F_IN; f++) {
        float w = W[f * H + c];
        float4 n0 = *(const float4*)&nfs[f][0];
        float4 n1 = *(const float4*)&nfs[f][4];
        acc[0] += n0.x * w; acc[1] += n0.y * w; acc[2] += n0.z * w; acc[3] += n0.w * w;
        acc[4] += n1.x * w; acc[5] += n1.y * w; acc[6] += n1.z * w; acc[7] += n1.w * w;
    }
#pragma unroll
    for (int r = 0; r < EMB_ROWS; r++) x[(row0 + r) * H + c] = acc[r];
}

// ---------------------------------------------------------------------------
// h[row, c] = sum_k x[row, k] * W[k, c]   (rows=B*N, K=H=256, cols=H=256)
// 32 rows/block; thread owns 2 cols x 16 rows.
__global__ __launch_bounds__(256) void k_gemm(const float* __restrict__ x,
                                              const float* __restrict__ W,
                                              float* __restrict__ h) {
    __shared__ float xs[256][36];               // xs[k][r], pad 36 (16B-aligned rows)
    const int row0 = blockIdx.x * 32;
    const int t = threadIdx.x;
    for (int idx = t; idx < 32 * 256; idx += 256) {
        int r = idx >> 8, k = idx & 255;
        xs[k][r] = x[(row0 + r) * H + k];
    }
    __syncthreads();
    const int cc = t & 127, rg = t >> 7;        // cols cc, cc+128; rows rg*16..+15
    float acc0[16], acc1[16];
#pragma unroll
    for (int r = 0; r < 16; r++) { acc0[r] = 0.f; acc1[r] = 0.f; }
#pragma unroll 2
    for (int k = 0; k < 256; k++) {
        float w0 = W[k * H + cc];
        float w1 = W[k * H + cc + 128];
        float4 xa = *(const float4*)&xs[k][rg * 16 + 0];
        float4 xb = *(const float4*)&xs[k][rg * 16 + 4];
        float4 xc = *(const float4*)&xs[k][rg * 16 + 8];
        float4 xd = *(const float4*)&xs[k][rg * 16 + 12];
        float xv[16] = {xa.x, xa.y, xa.z, xa.w, xb.x, xb.y, xb.z, xb.w,
                        xc.x, xc.y, xc.z, xc.w, xd.x, xd.y, xd.z, xd.w};
#pragma unroll
        for (int r = 0; r < 16; r++) { acc0[r] += xv[r] * w0; acc1[r] += xv[r] * w1; }
    }
#pragma unroll
    for (int r = 0; r < 16; r++) {
        h[(row0 + rg * 16 + r) * H + cc] = acc0[r];
        h[(row0 + rg * 16 + r) * H + cc + 128] = acc1[r];
    }
}

// ---------------------------------------------------------------------------
// s1[row] = h[row,:].a1 ; s2[row] = h[row,:].a2   (one wave per row)
__global__ __launch_bounds__(256) void k_s12(const float* __restrict__ h,
                                             const float* __restrict__ a1,
                                             const float* __restrict__ a2,
                                             float* __restrict__ s1, float* __restrict__ s2) {
    const int lane = threadIdx.x & 63;
    const int row = blockIdx.x * 4 + (threadIdx.x >> 6);
    const float* hr = h + row * H;
    float v1 = 0.f, v2 = 0.f;
#pragma unroll
    for (int q = 0; q < 4; q++) {
        float hv = hr[lane + 64 * q];
        v1 += hv * a1[lane + 64 * q];
        v2 += hv * a2[lane + 64 * q];
    }
    for (int off = 32; off; off >>= 1) { v1 += __shfl_down(v1, off); v2 += __shfl_down(v2, off); }
    if (lane == 0) { s1[row] = v1; s2[row] = v2; }
}

// ---------------------------------------------------------------------------
// Flash-style GAT: out[b,i,:] = relu( softmax_j(mask? leaky(s1_i+s2_j): NEG) @ h[b,:,:] )
// Block: 256 thr, 32 i-rows, j in tiles of 64. Wave ig owns rows ig*8..+7.
// Online softmax state (m,l) wave-replicated in registers; p transposed in LDS.
__global__ __launch_bounds__(256) void k_gat(const float* __restrict__ h,
                                             const float* __restrict__ s1,
                                             const float* __restrict__ s2,
                                             const unsigned long long* __restrict__ mask,
                                             float* __restrict__ out) {
    const int b = blockIdx.y;
    const int i0 = blockIdx.x * 32;
    const int t = threadIdx.x;
    const int lane = t & 63;
    const int ig = t >> 6;                      // wave id: rows ig*8 .. ig*8+7
    __shared__ float ps[64][36];                // p[jj][ii], stride 36 (16B-aligned)

    float m_row[8], l_row[8], s1v[8], scf[8];
    float acc[8][4];
#pragma unroll
    for (int r = 0; r < 8; r++) {
        m_row[r] = -INFINITY; l_row[r] = 0.f;
        s1v[r] = s1[b * N + i0 + ig * 8 + r];
#pragma unroll
        for (int q = 0; q < 4; q++) acc[r][q] = 0.f;
    }
    const float* hb = h + b * N * H;

    for (int jt = 0; jt < N / 64; jt++) {
        const int j0 = jt * 64;
        float s2v = s2[b * N + j0 + lane];
        // ---- phase 1: scores, online-softmax update (wave-local) ----
#pragma unroll
        for (int r = 0; r < 8; r++) {
            int i = i0 + ig * 8 + r;
            unsigned long long mw = mask[(b * N + i) * (N / 64) + jt];
            float sv = s1v[r] + s2v;
            float ev = sv >= 0.f ? sv : ALPHA * sv;
            float e = ((mw >> lane) & 1ull) ? ev : NEG;
            float mj = e;
            for (int off = 32; off; off >>= 1) mj = fmaxf(mj, __shfl_xor(mj, off));
            float mn = fmaxf(m_row[r], mj);
            float sc = __expf(m_row[r] - mn);
            float p = __expf(e - mn);
            float psum = p;
            for (int off = 32; off; off >>= 1) psum += __shfl_xor(psum, off);
            l_row[r] = l_row[r] * sc + psum;
            m_row[r] = mn;
            scf[r] = sc;
            ps[lane][ig * 8 + r] = p;
        }
        __syncthreads();
        // ---- phase 2: rescale + att@h FMA ----
#pragma unroll
        for (int r = 0; r < 8; r++) {
            float sc = scf[r];
#pragma unroll
            for (int q = 0; q < 4; q++) acc[r][q] *= sc;
        }
        const int cc = lane;                    // cols cc + 64q
#pragma unroll 2
        for (int jj = 0; jj < 64; jj++) {
            const float* hrow = hb + (j0 + jj) * H + cc;
            float h0 = hrow[0], h1 = hrow[64], h2 = hrow[128], h3 = hrow[192];
            float4 pa = *(const float4*)&ps[jj][ig * 8];
            float4 pb = *(const float4*)&ps[jj][ig * 8 + 4];
            float pv[8] = {pa.x, pa.y, pa.z, pa.w, pb.x, pb.y, pb.z, pb.w};
            float hv[4] = {h0, h1, h2, h3};
#pragma unroll
            for (int r = 0; r < 8; r++)
#pragma unroll
                for (int q = 0; q < 4; q++) acc[r][q] += pv[r] * hv[q];
        }
        __syncthreads();
    }
    // ---- epilogue: /l, relu, store ----
    const int cc = lane;
#pragma unroll
    for (int r = 0; r < 8; r++) {
        float inv = 1.f / l_row[r];
        float* orow = out + (b * N + i0 + ig * 8 + r) * H;
#pragma unroll
        for (int q = 0; q < 4; q++) orow[cc + 64 * q] = fmaxf(acc[r][q] * inv, 0.f);
    }
}

// ---------------------------------------------------------------------------
// pooling stage 1: per (b, chunk of 128 rows) partial sum & max over n
__global__ __launch_bounds__(256) void k_pool1(const float* __restrict__ x,
                                               float* __restrict__ psum, float* __restrict__ pmax) {
    const int b = blockIdx.x >> 3, chunk = blockIdx.x & 7;
    const int c = threadIdx.x;
    const float* xb = x + (b * N + chunk * 128) * H;
    float s = 0.f, m = -INFINITY;
    for (int n = 0; n < 128; n++) {
        float v = xb[n * H + c];
        s += v; m = fmaxf(m, v);
    }
    psum[blockIdx.x * H + c] = s;
    pmax[blockIdx.x * H + c] = m;
}

// pooling stage 2: finish mean+max, then 2-layer MLP -> g[b,:]
__global__ __launch_bounds__(256) void k_pool2(const float* __restrict__ psum,
                                               const float* __restrict__ pmax,
                                               const float* __restrict__ W1, const float* __restrict__ b1,
                                               const float* __restrict__ W2, const float* __restrict__ b2,
                                               float* __restrict__ gout) {
    __shared__ float g_s[H];
    __shared__ float t_s[H];
    const int b = blockIdx.x;
    const int c = threadIdx.x;
    float s = 0.f, m = -INFINITY;
#pragma unroll
    for (int ch = 0; ch < 8; ch++) {
        s += psum[(b * 8 + ch) * H + c];
        m = fmaxf(m, pmax[(b * 8 + ch) * H + c]);
    }
    g_s[c] = s * (1.f / N) + m;
    __syncthreads();
    float a = b1[c];
    for (int k = 0; k < H; k++) a += g_s[k] * W1[k * H + c];
    t_s[c] = fmaxf(a, 0.f);
    __syncthreads();
    float o = b2[c];
    for (int k = 0; k < H; k++) o += t_s[k] * W2[k * H + c];
    gout[b * H + c] = o;
}

// ---------------------------------------------------------------------------
extern "C" void kernel_launch(void* const* d_in, const int* in_sizes, int n_in,
                              void* d_out, int out_size, void* d_ws, size_t ws_size,
                              hipStream_t stream) {
    const float* nf    = (const float*)d_in[0];
    const float* adj   = (const float*)d_in[1];
    const float* emb_W = (const float*)d_in[2];
    const float* emb_b = (const float*)d_in[3];
    const float* W0    = (const float*)d_in[4];
    const float* a1_0  = (const float*)d_in[5];
    const float* a2_0  = (const float*)d_in[6];
    const float* W1    = (const float*)d_in[7];
    const float* a1_1  = (const float*)d_in[8];
    const float* a2_1  = (const float*)d_in[9];
    const float* gpW1  = (const float*)d_in[10];
    const float* gpb1  = (const float*)d_in[11];
    const float* gpW2  = (const float*)d_in[12];
    const float* gpb2  = (const float*)d_in[13];

    float* xout = (float*)d_out;                       // [B,N,H]
    float* gout = xout + B * N * H;                    // [B,H]

    float* ws = (float*)d_ws;
    float* x  = ws;                                    // 4194304 f
    float* h  = ws + 4194304;                          // 4194304 f
    float* s1 = ws + 8388608;                          // 16384 f
    float* s2 = ws + 8404992;                          // 16384 f
    unsigned long long* mask = (unsigned long long*)(ws + 8421376);   // 262144 u64
    float* psum = ws + 8421376 + 524288;               // 32768 f
    float* pmax = psum + 32768;                        // 32768 f

    k_mask<<<1024, 256, 0, stream>>>(adj, mask);
    k_embed<<<B * N / EMB_ROWS, 256, 0, stream>>>(nf, emb_W, emb_b, x);

    // layer 0
    k_gemm<<<B * N / 32, 256, 0, stream>>>(x, W0, h);
    k_s12<<<B * N / 4, 256, 0, stream>>>(h, a1_0, a2_0, s1, s2);
    k_gat<<<dim3(N / 32, B), 256, 0, stream>>>(h, s1, s2, mask, x);

    // layer 1 (writes x output directly to d_out)
    k_gemm<<<B * N / 32, 256, 0, stream>>>(x, W1, h);
    k_s12<<<B * N / 4, 256, 0, stream>>>(h, a1_1, a2_1, s1, s2);
    k_gat<<<dim3(N / 32, B), 256, 0, stream>>>(h, s1, s2, mask, xout);

    // global pooling + MLP
    k_pool1<<<B * 8, 256, 0, stream>>>(xout, psum, pmax);
    k_pool2<<<B, 256, 0, stream>>>(psum, pmax, gpW1, gpb1, gpW2, gpb2, gout);
}

// Round 2
// 638.194 us; speedup vs baseline: 1.6021x; 1.6021x over previous
//
#include <hip/hip_runtime.h>

#define B 16
#define N 1024
#define F_IN 64
#define H 256
#define ALPHA 0.2f

typedef __attribute__((ext_vector_type(8))) short short8;
typedef __attribute__((ext_vector_type(4))) float floatx4;

__device__ __forceinline__ unsigned rne_hi(float v) {
    unsigned b = __float_as_uint(v);
    return (b + 0x7FFFu + ((b >> 16) & 1u)) >> 16;
}
__device__ __forceinline__ float bf16val(unsigned hi) { return __uint_as_float(hi << 16); }

// ---------------------------------------------------------------------------
// adj [B,N,N] f32 -> bitmask u32 words: mask32[(b*N+i)*32 + j/32]
__global__ void k_mask(const float* __restrict__ adj, unsigned* __restrict__ mask32) {
    const int lane = threadIdx.x & 63;
    const int wave = blockIdx.x * 4 + (threadIdx.x >> 6);
    const int nwaves = gridDim.x * 4;
    const int words = B * N * (N / 64);
    for (int w = wave; w < words; w += nwaves) {
        float v = adj[(size_t)w * 64 + lane];
        unsigned long long m = __ballot(v > 0.f);
        if (lane == 0) { mask32[2 * w] = (unsigned)m; mask32[2 * w + 1] = (unsigned)(m >> 32); }
    }
}

// ---------------------------------------------------------------------------
// W [256x256] row-major -> transposed split bf16 W_t[c][k] (hi, lo), 2 layers
__global__ __launch_bounds__(256) void k_prep(const float* __restrict__ W0, const float* __restrict__ W1,
                                              ushort* __restrict__ wth, ushort* __restrict__ wtl) {
    __shared__ float ld[64][65];
    const int l = blockIdx.x >> 4;
    const int kt = (blockIdx.x >> 2) & 3, ct = blockIdx.x & 3;
    const float* W = l ? W1 : W0;
    const int t = threadIdx.x;
#pragma unroll
    for (int e = 0; e < 16; e++) {
        int idx = t + 256 * e;
        int kl = idx >> 6, cl = idx & 63;
        ld[kl][cl] = W[(kt * 64 + kl) * H + ct * 64 + cl];
    }
    __syncthreads();
    ushort* oh = wth + l * H * H;
    ushort* ol = wtl + l * H * H;
#pragma unroll
    for (int e = 0; e < 16; e++) {
        int idx = t + 256 * e;
        int cl = idx >> 6, kl = idx & 63;
        float v = ld[kl][cl];
        unsigned hi = rne_hi(v);
        float lo = v - bf16val(hi);
        oh[(ct * 64 + cl) * H + kt * 64 + kl] = (ushort)hi;
        ol[(ct * 64 + cl) * H + kt * 64 + kl] = (ushort)rne_hi(lo);
    }
}

// wa1[k] = sum_c W[k][c]*a1[c], wa2 likewise. One block per layer.
__global__ __launch_bounds__(256) void k_wa(const float* __restrict__ W0, const float* __restrict__ a10, const float* __restrict__ a20,
                                            const float* __restrict__ W1, const float* __restrict__ a11, const float* __restrict__ a21,
                                            float* __restrict__ wa1, float* __restrict__ wa2) {
    __shared__ float a1s[H], a2s[H];
    const int l = blockIdx.x;
    const float* W = l ? W1 : W0;
    const float* a1 = l ? a11 : a10;
    const float* a2 = l ? a21 : a20;
    const int t = threadIdx.x;
    a1s[t] = a1[t]; a2s[t] = a2[t];
    __syncthreads();
    float v1 = 0.f, v2 = 0.f;
    for (int c = 0; c < H; c += 4) {
        float4 w = *(const float4*)&W[t * H + c];
        v1 += w.x * a1s[c] + w.y * a1s[c + 1] + w.z * a1s[c + 2] + w.w * a1s[c + 3];
        v2 += w.x * a2s[c] + w.y * a2s[c + 1] + w.z * a2s[c + 2] + w.w * a2s[c + 3];
    }
    wa1[l * H + t] = v1;
    wa2[l * H + t] = v2;
}

// ---------------------------------------------------------------------------
// embed: x = nf @ emb_W + b -> split bf16 row-major x_hi/x_lo [B*N][H]
#define EMB_ROWS 8
__global__ __launch_bounds__(256) void k_embed(const float* __restrict__ nf,
                                               const float* __restrict__ W,
                                               const float* __restrict__ bias,
                                               ushort* __restrict__ xhi, ushort* __restrict__ xlo) {
    __shared__ float nfs[F_IN][EMB_ROWS];
    const int row0 = blockIdx.x * EMB_ROWS;
    const int t = threadIdx.x;
    for (int idx = t; idx < EMB_ROWS * F_IN; idx += 256) {
        int r = idx >> 6, f = idx & 63;
        nfs[f][r] = nf[(row0 + r) * F_IN + f];
    }
    __syncthreads();
    const int c = t;
    float acc[EMB_ROWS];
    float bv = bias[c];
#pragma unroll
    for (int r = 0; r < EMB_ROWS; r++) acc[r] = bv;
    for (int f = 0; f < F_IN; f++) {
        float w = W[f * H + c];
        float4 n0 = *(const float4*)&nfs[f][0];
        float4 n1 = *(const float4*)&nfs[f][4];
        acc[0] += n0.x * w; acc[1] += n0.y * w; acc[2] += n0.z * w; acc[3] += n0.w * w;
        acc[4] += n1.x * w; acc[5] += n1.y * w; acc[6] += n1.z * w; acc[7] += n1.w * w;
    }
#pragma unroll
    for (int r = 0; r < EMB_ROWS; r++) {
        float v = acc[r];
        unsigned hi = rne_hi(v);
        xhi[(size_t)(row0 + r) * H + c] = (ushort)hi;
        xlo[(size_t)(row0 + r) * H + c] = (ushort)rne_hi(v - bf16val(hi));
    }
}

// ---------------------------------------------------------------------------
// s1 = x.wa1, s2 = x.wa2 (x = hi+lo), plus per-b running max of s2 via atomicMax
__global__ __launch_bounds__(256) void k_s12(const ushort* __restrict__ xhi, const ushort* __restrict__ xlo,
                                             const float* __restrict__ wa1, const float* __restrict__ wa2,
                                             float* __restrict__ s1, float* __restrict__ s2,
                                             unsigned* __restrict__ s2maxkey) {
    __shared__ float smax[4];
    const int lane = threadIdx.x & 63;
    const int w = threadIdx.x >> 6;
    const int row = blockIdx.x * 4 + w;
    const int c0 = lane * 4;
    ushort4 h4 = *(const ushort4*)&xhi[(size_t)row * H + c0];
    ushort4 l4 = *(const ushort4*)&xlo[(size_t)row * H + c0];
    float4 w1 = *(const float4*)&wa1[c0];
    float4 w2 = *(const float4*)&wa2[c0];
    float x0 = bf16val(h4.x) + bf16val(l4.x);
    float x1 = bf16val(h4.y) + bf16val(l4.y);
    float x2 = bf16val(h4.z) + bf16val(l4.z);
    float x3 = bf16val(h4.w) + bf16val(l4.w);
    float v1 = x0 * w1.x + x1 * w1.y + x2 * w1.z + x3 * w1.w;
    float v2 = x0 * w2.x + x1 * w2.y + x2 * w2.z + x3 * w2.w;
    for (int off = 32; off; off >>= 1) { v1 += __shfl_down(v1, off); v2 += __shfl_down(v2, off); }
    if (lane == 0) { s1[row] = v1; s2[row] = v2; smax[w] = v2; }
    __syncthreads();
    if (threadIdx.x == 0) {
        float m = fmaxf(fmaxf(smax[0], smax[1]), fmaxf(smax[2], smax[3]));
        unsigned bt = __float_as_uint(m);
        unsigned key = (bt & 0x80000000u) ? ~bt : (bt | 0x80000000u);
        atomicMax(&s2maxkey[row >> 10], key);
    }
}

// ---------------------------------------------------------------------------
// h = x @ W via bf16x3 MFMA. Output transposed split bf16 h_t[b][c][n].
// Block: 32 rows; wave w: rows (w&1)*16, cols (w>>1)*128 (8 16-col tiles).
__global__ __launch_bounds__(256) void k_gemm(const ushort* __restrict__ xhi, const ushort* __restrict__ xlo,
                                              const ushort* __restrict__ wth, const ushort* __restrict__ wtl,
                                              ushort* __restrict__ hth, ushort* __restrict__ htl) {
    const int row0 = blockIdx.x * 32;
    const int t = threadIdx.x;
    const int lane = t & 63;
    const int w = t >> 6;
    const int rg = (w & 1) * 16, ch = (w >> 1) * 128;
    const int l15 = lane & 15, quad = lane >> 4;

    floatx4 acc[8];
    floatx4 z = {0.f, 0.f, 0.f, 0.f};
#pragma unroll
    for (int n = 0; n < 8; n++) acc[n] = z;

    const ushort* ah = xhi + (size_t)(row0 + rg + l15) * H + quad * 8;
    const ushort* al = xlo + (size_t)(row0 + rg + l15) * H + quad * 8;
    const ushort* bh = wth + (size_t)(ch + l15) * H + quad * 8;
    const ushort* bl = wtl + (size_t)(ch + l15) * H + quad * 8;

    for (int k0 = 0; k0 < H; k0 += 32) {
        short8 Ahi = *(const short8*)(ah + k0);
        short8 Alo = *(const short8*)(al + k0);
#pragma unroll
        for (int n = 0; n < 8; n++) {
            short8 Bhi = *(const short8*)(bh + n * 16 * H + k0);
            short8 Blo = *(const short8*)(bl + n * 16 * H + k0);
            acc[n] = __builtin_amdgcn_mfma_f32_16x16x32_bf16(Ahi, Bhi, acc[n], 0, 0, 0);
            acc[n] = __builtin_amdgcn_mfma_f32_16x16x32_bf16(Ahi, Blo, acc[n], 0, 0, 0);
            acc[n] = __builtin_amdgcn_mfma_f32_16x16x32_bf16(Alo, Bhi, acc[n], 0, 0, 0);
        }
    }
    // D: local row = quad*4+reg, col = ch + n*16 + l15. Store transposed.
    const int r0 = row0 + rg + quad * 4;
    const int b = r0 >> 10;
    const int n0 = r0 & 1023;
#pragma unroll
    for (int n = 0; n < 8; n++) {
        const int c = ch + n * 16 + l15;
        ushort4 ph, pl;
        float v0 = acc[n][0], v1 = acc[n][1], v2 = acc[n][2], v3 = acc[n][3];
        unsigned h0 = rne_hi(v0), h1 = rne_hi(v1), h2 = rne_hi(v2), h3 = rne_hi(v3);
        ph.x = (ushort)h0; ph.y = (ushort)h1; ph.z = (ushort)h2; ph.w = (ushort)h3;
        pl.x = (ushort)rne_hi(v0 - bf16val(h0));
        pl.y = (ushort)rne_hi(v1 - bf16val(h1));
        pl.z = (ushort)rne_hi(v2 - bf16val(h2));
        pl.w = (ushort)rne_hi(v3 - bf16val(h3));
        size_t o = ((size_t)(b * H + c) << 10) + n0;
        *(ushort4*)&hth[o] = ph;
        *(ushort4*)&htl[o] = pl;
    }
}

// ---------------------------------------------------------------------------
// GAT: out[i,:] = relu( (P/l) @ h ), P = exp(leaky(s1_i+s2_j)-m) masked, bf16 MFMA.
// Block: (b, 32 i-rows); wave w: rows (w&1)*16, cols (w>>1)*128.
template <int LAST>
__global__ __launch_bounds__(256) void k_gat(const ushort* __restrict__ hth, const ushort* __restrict__ htl,
                                             const float* __restrict__ s1, const float* __restrict__ s2,
                                             const unsigned* __restrict__ mask32,
                                             const unsigned* __restrict__ s2maxkey,
                                             float* __restrict__ outf,
                                             ushort* __restrict__ oxhi, ushort* __restrict__ oxlo) {
    __shared__ float l_s[32];
    const int b = blockIdx.y;
    const int i0 = blockIdx.x * 32;
    const int t = threadIdx.x;
    const int lane = t & 63, w = t >> 6;
    const int rg = (w & 1) * 16, ch = (w >> 1) * 128;
    const int l15 = lane & 15, quad = lane >> 4;

    unsigned key = s2maxkey[b];
    unsigned mb = (key & 0x80000000u) ? (key ^ 0x80000000u) : ~key;
    const float s2max = __uint_as_float(mb);

    const int i = i0 + rg + l15;
    const float s1v = s1[b * N + i];
    const float tmx = s1v + s2max;
    const float mrow = fmaxf(tmx, ALPHA * tmx);

    floatx4 acc[8];
    floatx4 z = {0.f, 0.f, 0.f, 0.f};
#pragma unroll
    for (int n = 0; n < 8; n++) acc[n] = z;
    float lsum = 0.f;

    const ushort* bh = hth + ((size_t)(b * H + ch + l15) << 10) + quad * 8;
    const ushort* bl = htl + ((size_t)(b * H + ch + l15) << 10) + quad * 8;
    const unsigned* mp = mask32 + (size_t)(b * N + i) * 32;
    const float* s2p = s2 + b * N + quad * 8;

    for (int jt = 0; jt < 32; jt++) {
        const unsigned mw = mp[jt];
        const unsigned mbyte = (mw >> (quad * 8)) & 0xffu;
        float4 sa = *(const float4*)(s2p + jt * 32);
        float4 sb = *(const float4*)(s2p + jt * 32 + 4);
        float sv[8] = {sa.x, sa.y, sa.z, sa.w, sb.x, sb.y, sb.z, sb.w};
        short8 A;
#pragma unroll
        for (int j = 0; j < 8; j++) {
            float e = s1v + sv[j];
            e = fmaxf(e, ALPHA * e);
            float p = __expf(e - mrow);
            p = ((mbyte >> j) & 1u) ? p : 0.f;
            unsigned hi = rne_hi(p);
            lsum += bf16val(hi);
            A[j] = (short)hi;
        }
        const ushort* bhj = bh + jt * 32;
        const ushort* blj = bl + jt * 32;
#pragma unroll
        for (int n = 0; n < 8; n++) {
            short8 Bhi = *(const short8*)(bhj + (size_t)n * 16384);
            short8 Blo = *(const short8*)(blj + (size_t)n * 16384);
            acc[n] = __builtin_amdgcn_mfma_f32_16x16x32_bf16(A, Bhi, acc[n], 0, 0, 0);
            acc[n] = __builtin_amdgcn_mfma_f32_16x16x32_bf16(A, Blo, acc[n], 0, 0, 0);
        }
    }
    lsum += __shfl_xor(lsum, 16);
    lsum += __shfl_xor(lsum, 32);
    if (quad == 0) l_s[rg + l15] = lsum;   // col-half waves write identical values
    __syncthreads();

    float inv[4];
#pragma unroll
    for (int r = 0; r < 4; r++) inv[r] = 1.f / l_s[rg + quad * 4 + r];
    const size_t rowbase = (size_t)(b << 10) + i0 + rg + quad * 4;
#pragma unroll
    for (int n = 0; n < 8; n++) {
        const int c = ch + n * 16 + l15;
#pragma unroll
        for (int r = 0; r < 4; r++) {
            float v = fmaxf(acc[n][r] * inv[r], 0.f);
            if (LAST) {
                outf[(rowbase + r) * H + c] = v;
            } else {
                unsigned hi = rne_hi(v);
                oxhi[(rowbase + r) * H + c] = (ushort)hi;
                oxlo[(rowbase + r) * H + c] = (ushort)rne_hi(v - bf16val(hi));
            }
        }
    }
}

// ---------------------------------------------------------------------------
__global__ __launch_bounds__(256) void k_pool1(const float* __restrict__ x,
                                               float* __restrict__ psum, float* __restrict__ pmax) {
    const int b = blockIdx.x >> 3, chunk = blockIdx.x & 7;
    const int c = threadIdx.x;
    const float* xb = x + (size_t)(b * N + chunk * 128) * H;
    float s = 0.f, m = -INFINITY;
    for (int n = 0; n < 128; n++) {
        float v = xb[(size_t)n * H + c];
        s += v; m = fmaxf(m, v);
    }
    psum[blockIdx.x * H + c] = s;
    pmax[blockIdx.x * H + c] = m;
}

__global__ __launch_bounds__(256) void k_pool2(const float* __restrict__ psum,
                                               const float* __restrict__ pmax,
                                               const float* __restrict__ W1, const float* __restrict__ b1,
                                               const float* __restrict__ W2, const float* __restrict__ b2,
                                               float* __restrict__ gout) {
    __shared__ float g_s[H];
    __shared__ float t_s[H];
    const int b = blockIdx.x;
    const int c = threadIdx.x;
    float s = 0.f, m = -INFINITY;
#pragma unroll
    for (int ch = 0; ch < 8; ch++) {
        s += psum[(b * 8 + ch) * H + c];
        m = fmaxf(m, pmax[(b * 8 + ch) * H + c]);
    }
    g_s[c] = s * (1.f / N) + m;
    __syncthreads();
    float a = b1[c];
    for (int k = 0; k < H; k++) a += g_s[k] * W1[k * H + c];
    t_s[c] = fmaxf(a, 0.f);
    __syncthreads();
    float o = b2[c];
    for (int k = 0; k < H; k++) o += t_s[k] * W2[k * H + c];
    gout[b * H + c] = o;
}

// ---------------------------------------------------------------------------
extern "C" void kernel_launch(void* const* d_in, const int* in_sizes, int n_in,
                              void* d_out, int out_size, void* d_ws, size_t ws_size,
                              hipStream_t stream) {
    const float* nf    = (const float*)d_in[0];
    const float* adj   = (const float*)d_in[1];
    const float* emb_W = (const float*)d_in[2];
    const float* emb_b = (const float*)d_in[3];
    const float* W0    = (const float*)d_in[4];
    const float* a1_0  = (const float*)d_in[5];
    const float* a2_0  = (const float*)d_in[6];
    const float* W1    = (const float*)d_in[7];
    const float* a1_1  = (const float*)d_in[8];
    const float* a2_1  = (const float*)d_in[9];
    const float* gpW1  = (const float*)d_in[10];
    const float* gpb1  = (const float*)d_in[11];
    const float* gpW2  = (const float*)d_in[12];
    const float* gpb2  = (const float*)d_in[13];

    float* xout = (float*)d_out;
    float* gout = xout + B * N * H;

    char* w = (char*)d_ws;
    ushort* xhi     = (ushort*)(w);
    ushort* xlo     = (ushort*)(w + 8388608);
    ushort* hth     = (ushort*)(w + 16777216);
    ushort* htl     = (ushort*)(w + 25165824);
    unsigned* mask32 = (unsigned*)(w + 33554432);
    float* s1       = (float*)(w + 35651584);
    float* s2       = (float*)(w + 35717120);
    ushort* wth     = (ushort*)(w + 35782656);
    ushort* wtl     = (ushort*)(w + 36044800);
    float* wa1      = (float*)(w + 36306944);
    float* wa2      = (float*)(w + 36308992);
    unsigned* keys  = (unsigned*)(w + 36311040);
    float* psum     = (float*)(w + 36311168);
    float* pmax     = (float*)(w + 36442240);

    hipMemsetAsync(keys, 0, 128, stream);
    k_mask<<<1024, 256, 0, stream>>>(adj, mask32);
    k_prep<<<32, 256, 0, stream>>>(W0, W1, wth, wtl);
    k_wa<<<2, 256, 0, stream>>>(W0, a1_0, a2_0, W1, a1_1, a2_1, wa1, wa2);
    k_embed<<<B * N / EMB_ROWS, 256, 0, stream>>>(nf, emb_W, emb_b, xhi, xlo);

    // layer 0
    k_s12<<<B * N / 4, 256, 0, stream>>>(xhi, xlo, wa1, wa2, s1, s2, keys);
    k_gemm<<<B * N / 32, 256, 0, stream>>>(xhi, xlo, wth, wtl, hth, htl);
    k_gat<0><<<dim3(N / 32, B), 256, 0, stream>>>(hth, htl, s1, s2, mask32, keys, nullptr, xhi, xlo);

    // layer 1
    k_s12<<<B * N / 4, 256, 0, stream>>>(xhi, xlo, wa1 + H, wa2 + H, s1, s2, keys + 16);
    k_gemm<<<B * N / 32, 256, 0, stream>>>(xhi, xlo, wth + H * H, wtl + H * H, hth, htl);
    k_gat<1><<<dim3(N / 32, B), 256, 0, stream>>>(hth, htl, s1, s2, mask32, keys + 16, xout, nullptr, nullptr);

    // pooling
    k_pool1<<<B * 8, 256, 0, stream>>>(xout, psum, pmax);
    k_pool2<<<B, 256, 0, stream>>>(psum, pmax, gpW1, gpb1, gpW2, gpb2, gout);
}

// Round 3
// 361.260 us; speedup vs baseline: 2.8302x; 1.7666x over previous
//
#include <hip/hip_runtime.h>

#define B 16
#define N 1024
#define F_IN 64
#define H 256
#define ALPHA 0.2f

typedef __attribute__((ext_vector_type(8))) short short8;
typedef __attribute__((ext_vector_type(4))) float floatx4;

typedef __attribute__((address_space(3))) void lds_void;
typedef const __attribute__((address_space(1))) void glb_void;
#define ASYNC16(gsrc, ldst) __builtin_amdgcn_global_load_lds((glb_void*)(gsrc), (lds_void*)(ldst), 16, 0, 0)

__device__ __forceinline__ unsigned rne_hi(float v) {
    unsigned b = __float_as_uint(v);
    return (b + 0x7FFFu + ((b >> 16) & 1u)) >> 16;
}
__device__ __forceinline__ float bf16val(unsigned hi) { return __uint_as_float(hi << 16); }

__device__ __forceinline__ floatx4 mfma16(short8 a, short8 b, floatx4 c) {
    return __builtin_amdgcn_mfma_f32_16x16x32_bf16(a, b, c, 0, 0, 0);
}

// ---------------------------------------------------------------------------
// adj [B,N,N] f32 -> bitmask u32: mask32[(b*N+i)*32 + j/32]
__global__ void k_mask(const float* __restrict__ adj, unsigned* __restrict__ mask32) {
    const int lane = threadIdx.x & 63;
    const int wave = blockIdx.x * 4 + (threadIdx.x >> 6);
    const int nwaves = gridDim.x * 4;
    const int words = B * N * (N / 64);
    for (int w = wave; w < words; w += nwaves) {
        float v = adj[(size_t)w * 64 + lane];
        unsigned long long m = __ballot(v > 0.f);
        if (lane == 0) { mask32[2 * w] = (unsigned)m; mask32[2 * w + 1] = (unsigned)(m >> 32); }
    }
}

// ---------------------------------------------------------------------------
// W [256x256] row-major -> transposed split bf16 W_t[c][k] (hi, lo), 2 layers
__global__ __launch_bounds__(256) void k_prep(const float* __restrict__ W0, const float* __restrict__ W1,
                                              ushort* __restrict__ wth, ushort* __restrict__ wtl) {
    __shared__ float ld[64][65];
    const int l = blockIdx.x >> 4;
    const int kt = (blockIdx.x >> 2) & 3, ct = blockIdx.x & 3;
    const float* W = l ? W1 : W0;
    const int t = threadIdx.x;
#pragma unroll
    for (int e = 0; e < 16; e++) {
        int idx = t + 256 * e;
        int kl = idx >> 6, cl = idx & 63;
        ld[kl][cl] = W[(kt * 64 + kl) * H + ct * 64 + cl];
    }
    __syncthreads();
    ushort* oh = wth + l * H * H;
    ushort* ol = wtl + l * H * H;
#pragma unroll
    for (int e = 0; e < 16; e++) {
        int idx = t + 256 * e;
        int cl = idx >> 6, kl = idx & 63;
        float v = ld[kl][cl];
        unsigned hi = rne_hi(v);
        float lo = v - bf16val(hi);
        oh[(ct * 64 + cl) * H + kt * 64 + kl] = (ushort)hi;
        ol[(ct * 64 + cl) * H + kt * 64 + kl] = (ushort)rne_hi(lo);
    }
}

// ---------------------------------------------------------------------------
// embed: x = nf @ emb_W + b -> split bf16 row-major x_hi/x_lo [B*N][H]
#define EMB_ROWS 8
__global__ __launch_bounds__(256) void k_embed(const float* __restrict__ nf,
                                               const float* __restrict__ W,
                                               const float* __restrict__ bias,
                                               ushort* __restrict__ xhi, ushort* __restrict__ xlo) {
    __shared__ float nfs[F_IN][EMB_ROWS];
    const int row0 = blockIdx.x * EMB_ROWS;
    const int t = threadIdx.x;
    for (int idx = t; idx < EMB_ROWS * F_IN; idx += 256) {
        int r = idx >> 6, f = idx & 63;
        nfs[f][r] = nf[(row0 + r) * F_IN + f];
    }
    __syncthreads();
    const int c = t;
    float acc[EMB_ROWS];
    float bv = bias[c];
#pragma unroll
    for (int r = 0; r < EMB_ROWS; r++) acc[r] = bv;
    for (int f = 0; f < F_IN; f++) {
        float w = W[f * H + c];
        float4 n0 = *(const float4*)&nfs[f][0];
        float4 n1 = *(const float4*)&nfs[f][4];
        acc[0] += n0.x * w; acc[1] += n0.y * w; acc[2] += n0.z * w; acc[3] += n0.w * w;
        acc[4] += n1.x * w; acc[5] += n1.y * w; acc[6] += n1.z * w; acc[7] += n1.w * w;
    }
#pragma unroll
    for (int r = 0; r < EMB_ROWS; r++) {
        float v = acc[r];
        unsigned hi = rne_hi(v);
        xhi[(size_t)(row0 + r) * H + c] = (ushort)hi;
        xlo[(size_t)(row0 + r) * H + c] = (ushort)rne_hi(v - bf16val(hi));
    }
}

// ---------------------------------------------------------------------------
// h = x @ W (bf16x3 MFMA). W staged in LDS frag-order via global_load_lds.
// Block: 64 rows, 512 thr / 8 waves. Wave w: n-tiles {2w,2w+1}, all 4 row-groups.
// Epilogue: h_t split-bf16 transposed store + fused s1/s2 + per-b s2max atomic.
__global__ __launch_bounds__(512) void k_gemm(const ushort* __restrict__ xhi, const ushort* __restrict__ xlo,
                                              const ushort* __restrict__ wth, const ushort* __restrict__ wtl,
                                              const float* __restrict__ a1, const float* __restrict__ a2,
                                              ushort* __restrict__ hth, ushort* __restrict__ htl,
                                              float* __restrict__ s1, float* __restrict__ s2,
                                              unsigned* __restrict__ s2maxkey) {
    __shared__ ushort tile[16384];          // [hi n0..15 | lo n0..15][quad][l15][8us]
    __shared__ float sr1[64][9], sr2[64][9];
    const int row0 = blockIdx.x * 64;
    const int t = threadIdx.x;
    const int lane = t & 63, w = t >> 6;
    const int l15 = lane & 15, quad = lane >> 4;
    const int nb = 2 * w;

    floatx4 acc[4][2];
    floatx4 z = {0.f, 0.f, 0.f, 0.f};
#pragma unroll
    for (int rg = 0; rg < 4; rg++) { acc[rg][0] = z; acc[rg][1] = z; }

    for (int ks = 0; ks < 8; ks++) {
        const int k0 = ks * 32;
#pragma unroll
        for (int i2 = 0; i2 < 4; i2++) {
            int e = w * 4 + i2;
            const ushort* sb = (e < 16) ? wth : wtl;
            int n = e & 15;
            const ushort* src = sb + (size_t)(n * 16 + l15) * H + k0 + quad * 8;
            ASYNC16(src, &tile[e * 512]);
        }
        short8 Ahi[4], Alo[4];
#pragma unroll
        for (int rg = 0; rg < 4; rg++) {
            Ahi[rg] = *(const short8*)(xhi + (size_t)(row0 + rg * 16 + l15) * H + k0 + quad * 8);
            Alo[rg] = *(const short8*)(xlo + (size_t)(row0 + rg * 16 + l15) * H + k0 + quad * 8);
        }
        __syncthreads();
        short8 Bh0 = *(const short8*)&tile[nb * 512 + quad * 128 + l15 * 8];
        short8 Bh1 = *(const short8*)&tile[(nb + 1) * 512 + quad * 128 + l15 * 8];
        short8 Bl0 = *(const short8*)&tile[8192 + nb * 512 + quad * 128 + l15 * 8];
        short8 Bl1 = *(const short8*)&tile[8192 + (nb + 1) * 512 + quad * 128 + l15 * 8];
#pragma unroll
        for (int rg = 0; rg < 4; rg++) {
            acc[rg][0] = mfma16(Ahi[rg], Bh0, acc[rg][0]);
            acc[rg][0] = mfma16(Ahi[rg], Bl0, acc[rg][0]);
            acc[rg][0] = mfma16(Alo[rg], Bh0, acc[rg][0]);
            acc[rg][1] = mfma16(Ahi[rg], Bh1, acc[rg][1]);
            acc[rg][1] = mfma16(Ahi[rg], Bl1, acc[rg][1]);
            acc[rg][1] = mfma16(Alo[rg], Bh1, acc[rg][1]);
        }
        __syncthreads();
    }

    // ---- epilogue: transposed split-bf16 h store ----
    const int bb = row0 >> 10;
#pragma unroll
    for (int rg = 0; rg < 4; rg++) {
        const int r0g = row0 + rg * 16 + quad * 4;
        const int nIdx = r0g & 1023;
#pragma unroll
        for (int n2 = 0; n2 < 2; n2++) {
            const int c = (nb + n2) * 16 + l15;
            float v0 = acc[rg][n2][0], v1 = acc[rg][n2][1], v2 = acc[rg][n2][2], v3 = acc[rg][n2][3];
            unsigned h0 = rne_hi(v0), h1 = rne_hi(v1), h2 = rne_hi(v2), h3 = rne_hi(v3);
            ushort4 ph, pl;
            ph.x = (ushort)h0; ph.y = (ushort)h1; ph.z = (ushort)h2; ph.w = (ushort)h3;
            pl.x = (ushort)rne_hi(v0 - bf16val(h0));
            pl.y = (ushort)rne_hi(v1 - bf16val(h1));
            pl.z = (ushort)rne_hi(v2 - bf16val(h2));
            pl.w = (ushort)rne_hi(v3 - bf16val(h3));
            size_t o = ((size_t)(bb * H + c) << 10) + nIdx;
            *(ushort4*)&hth[o] = ph;
            *(ushort4*)&htl[o] = pl;
        }
    }
    // ---- fused s1/s2 ----
    float a1c0 = a1[nb * 16 + l15], a1c1 = a1[(nb + 1) * 16 + l15];
    float a2c0 = a2[nb * 16 + l15], a2c1 = a2[(nb + 1) * 16 + l15];
    float pr1[4][4], pr2[4][4];
#pragma unroll
    for (int rg = 0; rg < 4; rg++)
#pragma unroll
        for (int r = 0; r < 4; r++) {
            pr1[rg][r] = acc[rg][0][r] * a1c0 + acc[rg][1][r] * a1c1;
            pr2[rg][r] = acc[rg][0][r] * a2c0 + acc[rg][1][r] * a2c1;
        }
#pragma unroll
    for (int off = 1; off <= 8; off <<= 1)
#pragma unroll
        for (int rg = 0; rg < 4; rg++)
#pragma unroll
            for (int r = 0; r < 4; r++) {
                pr1[rg][r] += __shfl_xor(pr1[rg][r], off);
                pr2[rg][r] += __shfl_xor(pr2[rg][r], off);
            }
    if (l15 == 0) {
#pragma unroll
        for (int rg = 0; rg < 4; rg++)
#pragma unroll
            for (int r = 0; r < 4; r++) {
                int row = rg * 16 + quad * 4 + r;
                sr1[row][w] = pr1[rg][r];
                sr2[row][w] = pr2[rg][r];
            }
    }
    __syncthreads();
    if (t < 64) {
        float v1 = 0.f, v2 = 0.f;
#pragma unroll
        for (int ww = 0; ww < 8; ww++) { v1 += sr1[t][ww]; v2 += sr2[t][ww]; }
        s1[row0 + t] = v1;
        s2[row0 + t] = v2;
        float m = v2;
#pragma unroll
        for (int off = 1; off <= 32; off <<= 1) m = fmaxf(m, __shfl_xor(m, off));
        if (t == 0) {
            unsigned bt = __float_as_uint(m);
            unsigned key = (bt & 0x80000000u) ? ~bt : (bt | 0x80000000u);
            atomicMax(&s2maxkey[bb], key);
        }
    }
}

// ---------------------------------------------------------------------------
// GAT: out = relu((P/l) @ (h_hi+h_lo)). h staged to LDS frag-order; P shared via
// LDS (waves 0-3 generate for their 16-row group). 64 rows x 256 c per block.
template <int LAST>
__global__ __launch_bounds__(512) void k_gat(const ushort* __restrict__ hth, const ushort* __restrict__ htl,
                                             const float* __restrict__ s1, const float* __restrict__ s2,
                                             const unsigned* __restrict__ mask32,
                                             const unsigned* __restrict__ s2maxkey,
                                             float* __restrict__ outf,
                                             ushort* __restrict__ oxhi, ushort* __restrict__ oxlo,
                                             float* __restrict__ psum, float* __restrict__ pmax) {
    __shared__ ushort tile[16384];          // [hi n0..15 | lo n0..15][quad][l15][8us]
    __shared__ ushort p_s[2048];            // [rg][quad][l15][8us]
    __shared__ float l_s[64];
    const int lin = blockIdx.x;
    // XCD swizzle: batch b pinned to ~1 XCD pair for h_t L2 residency
    const int xcd = lin & 7, sl = lin >> 3;
    const int b = xcd * 2 + (sl & 1);
    const int chunk = sl >> 1;
    const int i0 = chunk * 64;
    const int t = threadIdx.x;
    const int lane = t & 63, w = t >> 6;
    const int l15 = lane & 15, quad = lane >> 4;
    const int nb = 2 * w;

    unsigned key = s2maxkey[b];
    unsigned mb = (key & 0x80000000u) ? (key ^ 0x80000000u) : ~key;
    const float s2max = __uint_as_float(mb);

    floatx4 acc[4][2];
    floatx4 z = {0.f, 0.f, 0.f, 0.f};
#pragma unroll
    for (int rg = 0; rg < 4; rg++) { acc[rg][0] = z; acc[rg][1] = z; }

    float s1v = 0.f, mrow = 0.f, lacc = 0.f;
    const unsigned* mp = mask32;
    if (w < 4) {
        int i = i0 + w * 16 + l15;
        s1v = s1[b * N + i];
        float tmx = s1v + s2max;
        mrow = fmaxf(tmx, ALPHA * tmx);
        mp = mask32 + (size_t)(b * N + i) * 32;
    }
    const ushort* hbh = hth + ((size_t)(b * H) << 10);
    const ushort* hbl = htl + ((size_t)(b * H) << 10);
    const float* s2b = s2 + b * N;

    for (int jt = 0; jt < 32; jt++) {
        const int j0 = jt * 32;
#pragma unroll
        for (int i2 = 0; i2 < 4; i2++) {
            int e = w * 4 + i2;
            const ushort* sb = (e < 16) ? hbh : hbl;
            int n = e & 15;
            const ushort* src = sb + (((size_t)(n * 16 + l15)) << 10) + j0 + quad * 8;
            ASYNC16(src, &tile[e * 512]);
        }
        if (w < 4) {
            unsigned mw = mp[jt];
            unsigned mbyte = (mw >> (quad * 8)) & 0xffu;
            float4 sa = *(const float4*)(s2b + j0 + quad * 8);
            float4 sbv = *(const float4*)(s2b + j0 + quad * 8 + 4);
            float sv[8] = {sa.x, sa.y, sa.z, sa.w, sbv.x, sbv.y, sbv.z, sbv.w};
            short8 A;
            float ls = 0.f;
#pragma unroll
            for (int j = 0; j < 8; j++) {
                float e1 = s1v + sv[j];
                e1 = fmaxf(e1, ALPHA * e1);
                float p = __expf(e1 - mrow);
                p = ((mbyte >> j) & 1u) ? p : 0.f;
                unsigned hi = rne_hi(p);
                ls += bf16val(hi);
                A[j] = (short)hi;
            }
            ls += __shfl_xor(ls, 16);
            ls += __shfl_xor(ls, 32);
            lacc += ls;
            *(short8*)&p_s[w * 512 + quad * 128 + l15 * 8] = A;
        }
        __syncthreads();
        short8 Ap[4];
#pragma unroll
        for (int rg = 0; rg < 4; rg++)
            Ap[rg] = *(const short8*)&p_s[rg * 512 + quad * 128 + l15 * 8];
        short8 Bh0 = *(const short8*)&tile[nb * 512 + quad * 128 + l15 * 8];
        short8 Bh1 = *(const short8*)&tile[(nb + 1) * 512 + quad * 128 + l15 * 8];
        short8 Bl0 = *(const short8*)&tile[8192 + nb * 512 + quad * 128 + l15 * 8];
        short8 Bl1 = *(const short8*)&tile[8192 + (nb + 1) * 512 + quad * 128 + l15 * 8];
#pragma unroll
        for (int rg = 0; rg < 4; rg++) {
            acc[rg][0] = mfma16(Ap[rg], Bh0, acc[rg][0]);
            acc[rg][0] = mfma16(Ap[rg], Bl0, acc[rg][0]);
            acc[rg][1] = mfma16(Ap[rg], Bh1, acc[rg][1]);
            acc[rg][1] = mfma16(Ap[rg], Bl1, acc[rg][1]);
        }
        __syncthreads();
    }
    if (w < 4 && quad == 0) l_s[w * 16 + l15] = lacc;
    __syncthreads();

    float inv[4][4];
#pragma unroll
    for (int rg = 0; rg < 4; rg++)
#pragma unroll
        for (int r = 0; r < 4; r++) inv[rg][r] = 1.f / l_s[rg * 16 + quad * 4 + r];

    const size_t rbase = (size_t)b * N + i0;
    float colsum[2] = {0.f, 0.f}, colmax[2] = {-INFINITY, -INFINITY};
#pragma unroll
    for (int rg = 0; rg < 4; rg++)
#pragma unroll
        for (int n2 = 0; n2 < 2; n2++) {
            const int c = (nb + n2) * 16 + l15;
#pragma unroll
            for (int r = 0; r < 4; r++) {
                float v = fmaxf(acc[rg][n2][r] * inv[rg][r], 0.f);
                const size_t row = rbase + rg * 16 + quad * 4 + r;
                if (LAST) {
                    outf[row * H + c] = v;
                    colsum[n2] += v;
                    colmax[n2] = fmaxf(colmax[n2], v);
                } else {
                    unsigned hi = rne_hi(v);
                    oxhi[row * H + c] = (ushort)hi;
                    oxlo[row * H + c] = (ushort)rne_hi(v - bf16val(hi));
                }
            }
        }
    if (LAST) {
#pragma unroll
        for (int n2 = 0; n2 < 2; n2++) {
            float s = colsum[n2], m = colmax[n2];
            s += __shfl_xor(s, 16); s += __shfl_xor(s, 32);
            m = fmaxf(m, __shfl_xor(m, 16)); m = fmaxf(m, __shfl_xor(m, 32));
            if (quad == 0) {
                const int c = (nb + n2) * 16 + l15;
                psum[(b * 16 + chunk) * H + c] = s;
                pmax[(b * 16 + chunk) * H + c] = m;
            }
        }
    }
}

// ---------------------------------------------------------------------------
// finish mean+max over 16 chunk-partials, then 2-layer MLP -> g[b,:]
__global__ __launch_bounds__(256) void k_pool2(const float* __restrict__ psum,
                                               const float* __restrict__ pmax,
                                               const float* __restrict__ W1, const float* __restrict__ b1,
                                               const float* __restrict__ W2, const float* __restrict__ b2,
                                               float* __restrict__ gout) {
    __shared__ float g_s[H];
    __shared__ float t_s[H];
    const int b = blockIdx.x;
    const int c = threadIdx.x;
    float s = 0.f, m = -INFINITY;
#pragma unroll
    for (int ch = 0; ch < 16; ch++) {
        s += psum[(b * 16 + ch) * H + c];
        m = fmaxf(m, pmax[(b * 16 + ch) * H + c]);
    }
    g_s[c] = s * (1.f / N) + m;
    __syncthreads();
    float a = b1[c];
    for (int k = 0; k < H; k++) a += g_s[k] * W1[k * H + c];
    t_s[c] = fmaxf(a, 0.f);
    __syncthreads();
    float o = b2[c];
    for (int k = 0; k < H; k++) o += t_s[k] * W2[k * H + c];
    gout[b * H + c] = o;
}

// ---------------------------------------------------------------------------
extern "C" void kernel_launch(void* const* d_in, const int* in_sizes, int n_in,
                              void* d_out, int out_size, void* d_ws, size_t ws_size,
                              hipStream_t stream) {
    const float* nf    = (const float*)d_in[0];
    const float* adj   = (const float*)d_in[1];
    const float* emb_W = (const float*)d_in[2];
    const float* emb_b = (const float*)d_in[3];
    const float* W0    = (const float*)d_in[4];
    const float* a1_0  = (const float*)d_in[5];
    const float* a2_0  = (const float*)d_in[6];
    const float* W1    = (const float*)d_in[7];
    const float* a1_1  = (const float*)d_in[8];
    const float* a2_1  = (const float*)d_in[9];
    const float* gpW1  = (const float*)d_in[10];
    const float* gpb1  = (const float*)d_in[11];
    const float* gpW2  = (const float*)d_in[12];
    const float* gpb2  = (const float*)d_in[13];

    float* xout = (float*)d_out;
    float* gout = xout + B * N * H;

    char* w = (char*)d_ws;
    ushort* xhi      = (ushort*)(w);
    ushort* xlo      = (ushort*)(w + 8388608);
    ushort* hth      = (ushort*)(w + 16777216);
    ushort* htl      = (ushort*)(w + 25165824);
    unsigned* mask32 = (unsigned*)(w + 33554432);
    float* s1        = (float*)(w + 35651584);
    float* s2        = (float*)(w + 35717120);
    ushort* wth      = (ushort*)(w + 35782656);
    ushort* wtl      = (ushort*)(w + 36044800);
    unsigned* keys   = (unsigned*)(w + 36306944);
    // psum/pmax overlay xhi (dead after gemm<1> reads it; gat<1> writes these)
    float* psum      = (float*)(w);
    float* pmax      = (float*)(w + 262144);

    hipMemsetAsync(keys, 0, 128, stream);
    k_mask<<<1024, 256, 0, stream>>>(adj, mask32);
    k_prep<<<32, 256, 0, stream>>>(W0, W1, wth, wtl);
    k_embed<<<B * N / EMB_ROWS, 256, 0, stream>>>(nf, emb_W, emb_b, xhi, xlo);

    // layer 0
    k_gemm<<<B * N / 64, 512, 0, stream>>>(xhi, xlo, wth, wtl, a1_0, a2_0,
                                           hth, htl, s1, s2, keys);
    k_gat<0><<<B * N / 64, 512, 0, stream>>>(hth, htl, s1, s2, mask32, keys,
                                             nullptr, xhi, xlo, nullptr, nullptr);

    // layer 1
    k_gemm<<<B * N / 64, 512, 0, stream>>>(xhi, xlo, wth + H * H, wtl + H * H, a1_1, a2_1,
                                           hth, htl, s1, s2, keys + 16);
    k_gat<1><<<B * N / 64, 512, 0, stream>>>(hth, htl, s1, s2, mask32, keys + 16,
                                             xout, nullptr, nullptr, psum, pmax);

    // pooling MLP
    k_pool2<<<B, 256, 0, stream>>>(psum, pmax, gpW1, gpb1, gpW2, gpb2, gout);
}

// Round 4
// 355.468 us; speedup vs baseline: 2.8763x; 1.0163x over previous
//
#include <hip/hip_runtime.h>

#define B 16
#define N 1024
#define F_IN 64
#define H 256
#define ALPHA 0.2f

typedef __attribute__((ext_vector_type(8))) short short8;
typedef __attribute__((ext_vector_type(4))) float floatx4;

typedef __attribute__((address_space(3))) void lds_void;
typedef const __attribute__((address_space(1))) void glb_void;
#define ASYNC16(gsrc, ldst) __builtin_amdgcn_global_load_lds((glb_void*)(gsrc), (lds_void*)(ldst), 16, 0, 0)

__device__ __forceinline__ unsigned rne_hi(float v) {
    unsigned b = __float_as_uint(v);
    return (b + 0x7FFFu + ((b >> 16) & 1u)) >> 16;
}
__device__ __forceinline__ float bf16val(unsigned hi) { return __uint_as_float(hi << 16); }

__device__ __forceinline__ floatx4 mfma16(short8 a, short8 b, floatx4 c) {
    return __builtin_amdgcn_mfma_f32_16x16x32_bf16(a, b, c, 0, 0, 0);
}

// ---------------------------------------------------------------------------
// adj [B,N,N] f32 -> bitmask u32: mask32[(b*N+i)*32 + j/32]
__global__ void k_mask(const float* __restrict__ adj, unsigned* __restrict__ mask32) {
    const int lane = threadIdx.x & 63;
    const int wave = blockIdx.x * 4 + (threadIdx.x >> 6);
    const int nwaves = gridDim.x * 4;
    const int words = B * N * (N / 64);
    for (int w = wave; w < words; w += nwaves) {
        float v = adj[(size_t)w * 64 + lane];
        unsigned long long m = __ballot(v > 0.f);
        if (lane == 0) { mask32[2 * w] = (unsigned)m; mask32[2 * w + 1] = (unsigned)(m >> 32); }
    }
}

// ---------------------------------------------------------------------------
// blocks 0-31: W -> transposed split bf16 W_t[c][k]; blocks 32-33: wa = W@a
__global__ __launch_bounds__(256) void k_prep(const float* __restrict__ W0, const float* __restrict__ W1,
                                              const float* __restrict__ a10, const float* __restrict__ a20,
                                              const float* __restrict__ a11, const float* __restrict__ a21,
                                              ushort* __restrict__ wth, ushort* __restrict__ wtl,
                                              float* __restrict__ wa1, float* __restrict__ wa2) {
    __shared__ float ld[64][65];
    const int t = threadIdx.x;
    if (blockIdx.x >= 32) {
        const int l = blockIdx.x - 32;
        const float* W = l ? W1 : W0;
        const float* a1 = l ? a11 : a10;
        const float* a2 = l ? a21 : a20;
        float* a1s = &ld[0][0];
        float* a2s = &ld[32][0];
        a1s[t] = a1[t]; a2s[t] = a2[t];
        __syncthreads();
        float v1 = 0.f, v2 = 0.f;
        for (int c = 0; c < H; c += 4) {
            float4 w = *(const float4*)&W[t * H + c];
            v1 += w.x * a1s[c] + w.y * a1s[c + 1] + w.z * a1s[c + 2] + w.w * a1s[c + 3];
            v2 += w.x * a2s[c] + w.y * a2s[c + 1] + w.z * a2s[c + 2] + w.w * a2s[c + 3];
        }
        wa1[l * H + t] = v1;
        wa2[l * H + t] = v2;
        return;
    }
    const int l = blockIdx.x >> 4;
    const int kt = (blockIdx.x >> 2) & 3, ct = blockIdx.x & 3;
    const float* W = l ? W1 : W0;
#pragma unroll
    for (int e = 0; e < 16; e++) {
        int idx = t + 256 * e;
        int kl = idx >> 6, cl = idx & 63;
        ld[kl][cl] = W[(kt * 64 + kl) * H + ct * 64 + cl];
    }
    __syncthreads();
    ushort* oh = wth + l * H * H;
    ushort* ol = wtl + l * H * H;
#pragma unroll
    for (int e = 0; e < 16; e++) {
        int idx = t + 256 * e;
        int cl = idx >> 6, kl = idx & 63;
        float v = ld[kl][cl];
        unsigned hi = rne_hi(v);
        float lo = v - bf16val(hi);
        oh[(ct * 64 + cl) * H + kt * 64 + kl] = (ushort)hi;
        ol[(ct * 64 + cl) * H + kt * 64 + kl] = (ushort)rne_hi(lo);
    }
}

// ---------------------------------------------------------------------------
// embed: x = nf @ emb_W + b -> split bf16 row-major x_hi/x_lo [B*N][H]
#define EMB_ROWS 8
__global__ __launch_bounds__(256) void k_embed(const float* __restrict__ nf,
                                               const float* __restrict__ W,
                                               const float* __restrict__ bias,
                                               ushort* __restrict__ xhi, ushort* __restrict__ xlo) {
    __shared__ float nfs[F_IN][EMB_ROWS];
    const int row0 = blockIdx.x * EMB_ROWS;
    const int t = threadIdx.x;
    for (int idx = t; idx < EMB_ROWS * F_IN; idx += 256) {
        int r = idx >> 6, f = idx & 63;
        nfs[f][r] = nf[(row0 + r) * F_IN + f];
    }
    __syncthreads();
    const int c = t;
    float acc[EMB_ROWS];
    float bv = bias[c];
#pragma unroll
    for (int r = 0; r < EMB_ROWS; r++) acc[r] = bv;
    for (int f = 0; f < F_IN; f++) {
        float w = W[f * H + c];
        float4 n0 = *(const float4*)&nfs[f][0];
        float4 n1 = *(const float4*)&nfs[f][4];
        acc[0] += n0.x * w; acc[1] += n0.y * w; acc[2] += n0.z * w; acc[3] += n0.w * w;
        acc[4] += n1.x * w; acc[5] += n1.y * w; acc[6] += n1.z * w; acc[7] += n1.w * w;
    }
#pragma unroll
    for (int r = 0; r < EMB_ROWS; r++) {
        float v = acc[r];
        unsigned hi = rne_hi(v);
        xhi[(size_t)(row0 + r) * H + c] = (ushort)hi;
        xlo[(size_t)(row0 + r) * H + c] = (ushort)rne_hi(v - bf16val(hi));
    }
}

// ---------------------------------------------------------------------------
// h = x @ W (bf16x3 MFMA). 256 thr, 32 rows x 128 c per block; B dbuf in LDS,
// one barrier per ks; A-frags global->reg prefetched. chalf0/w0 computes
// s1 = x.wa1, s2 = x.wa2 (exact) + per-b s2max atomic.
__global__ __launch_bounds__(256, 4) void k_gemm(const ushort* __restrict__ xhi, const ushort* __restrict__ xlo,
                                                 const ushort* __restrict__ wth, const ushort* __restrict__ wtl,
                                                 const float* __restrict__ wa1, const float* __restrict__ wa2,
                                                 ushort* __restrict__ hth, ushort* __restrict__ htl,
                                                 float* __restrict__ s1, float* __restrict__ s2,
                                                 unsigned* __restrict__ s2maxkey) {
    __shared__ __align__(16) ushort tile[2][8192];  // B: e=[hilo*8+n][quad][l15][8us]
    const int lin = blockIdx.x;
    const int rc = lin >> 1, chalf = lin & 1;
    const int row0 = rc * 32;
    const int t = threadIdx.x;
    const int lane = t & 63, w = t >> 6;            // 4 waves
    const int l15 = lane & 15, quad = lane >> 4;
    const int nb = 2 * w;
    const int fo = quad * 128 + l15 * 8;

    const ushort* wthh = wth + (size_t)(chalf * 128) * H;
    const ushort* wtlh = wtl + (size_t)(chalf * 128) * H;
    const ushort* srcb[4];
#pragma unroll
    for (int i2 = 0; i2 < 4; i2++) {
        int e = w * 4 + i2;
        const ushort* sb = (e < 8) ? wthh : wtlh;
        int n = e & 7;
        srcb[i2] = sb + (size_t)(n * 16 + l15) * H + quad * 8;
    }
    const ushort* ah0 = xhi + (size_t)(row0 + l15) * H + quad * 8;
    const ushort* al0 = xlo + (size_t)(row0 + l15) * H + quad * 8;
    const ushort* ah1 = xhi + (size_t)(row0 + 16 + l15) * H + quad * 8;
    const ushort* al1 = xlo + (size_t)(row0 + 16 + l15) * H + quad * 8;

    floatx4 acc[2][2];
    floatx4 z = {0.f, 0.f, 0.f, 0.f};
    acc[0][0] = z; acc[0][1] = z; acc[1][0] = z; acc[1][1] = z;
    float sp1a = 0.f, sp2a = 0.f, sp1b = 0.f, sp2b = 0.f;

    // prologue: stage B[0], load A[0]
#pragma unroll
    for (int i2 = 0; i2 < 4; i2++) ASYNC16(srcb[i2], &tile[0][(w * 4 + i2) * 512]);
    short8 A0h = *(const short8*)ah0;
    short8 A0l = *(const short8*)al0;
    short8 A1h = *(const short8*)ah1;
    short8 A1l = *(const short8*)al1;
    __syncthreads();

#pragma unroll
    for (int ks = 0; ks < 8; ks++) {
        const int cur = ks & 1, nxt = cur ^ 1;
        if (ks < 7) {
            const int k0n = (ks + 1) * 32;
#pragma unroll
            for (int i2 = 0; i2 < 4; i2++) ASYNC16(srcb[i2] + k0n, &tile[nxt][(w * 4 + i2) * 512]);
        }
        short8 A0h_n = {}, A0l_n = {}, A1h_n = {}, A1l_n = {};
        if (ks < 7) {
            const int k0n = (ks + 1) * 32;
            A0h_n = *(const short8*)(ah0 + k0n);
            A0l_n = *(const short8*)(al0 + k0n);
            A1h_n = *(const short8*)(ah1 + k0n);
            A1l_n = *(const short8*)(al1 + k0n);
        }
        short8 Bh0 = *(const short8*)&tile[cur][nb * 512 + fo];
        short8 Bh1 = *(const short8*)&tile[cur][(nb + 1) * 512 + fo];
        short8 Bl0 = *(const short8*)&tile[cur][(8 + nb) * 512 + fo];
        short8 Bl1 = *(const short8*)&tile[cur][(8 + nb + 1) * 512 + fo];
        acc[0][0] = mfma16(A0h, Bh0, acc[0][0]);
        acc[0][0] = mfma16(A0h, Bl0, acc[0][0]);
        acc[0][0] = mfma16(A0l, Bh0, acc[0][0]);
        acc[0][1] = mfma16(A0h, Bh1, acc[0][1]);
        acc[0][1] = mfma16(A0h, Bl1, acc[0][1]);
        acc[0][1] = mfma16(A0l, Bh1, acc[0][1]);
        acc[1][0] = mfma16(A1h, Bh0, acc[1][0]);
        acc[1][0] = mfma16(A1h, Bl0, acc[1][0]);
        acc[1][0] = mfma16(A1l, Bh0, acc[1][0]);
        acc[1][1] = mfma16(A1h, Bh1, acc[1][1]);
        acc[1][1] = mfma16(A1h, Bl1, acc[1][1]);
        acc[1][1] = mfma16(A1l, Bh1, acc[1][1]);
        if (chalf == 0 && w == 0) {
            float4 w1a = *(const float4*)(wa1 + ks * 32 + quad * 8);
            float4 w1b = *(const float4*)(wa1 + ks * 32 + quad * 8 + 4);
            float4 w2a = *(const float4*)(wa2 + ks * 32 + quad * 8);
            float4 w2b = *(const float4*)(wa2 + ks * 32 + quad * 8 + 4);
            float wv1[8] = {w1a.x, w1a.y, w1a.z, w1a.w, w1b.x, w1b.y, w1b.z, w1b.w};
            float wv2[8] = {w2a.x, w2a.y, w2a.z, w2a.w, w2b.x, w2b.y, w2b.z, w2b.w};
#pragma unroll
            for (int j = 0; j < 8; j++) {
                float xa = bf16val((ushort)A0h[j]) + bf16val((ushort)A0l[j]);
                float xb = bf16val((ushort)A1h[j]) + bf16val((ushort)A1l[j]);
                sp1a += xa * wv1[j]; sp2a += xa * wv2[j];
                sp1b += xb * wv1[j]; sp2b += xb * wv2[j];
            }
        }
        __syncthreads();
        if (ks < 7) { A0h = A0h_n; A0l = A0l_n; A1h = A1h_n; A1l = A1l_n; }
    }

    // ---- h store (transposed split bf16) ----
    const int bb = row0 >> 10;
#pragma unroll
    for (int rg = 0; rg < 2; rg++) {
        const int nIdx = (row0 + rg * 16 + quad * 4) & 1023;
#pragma unroll
        for (int n2 = 0; n2 < 2; n2++) {
            const int c = chalf * 128 + (nb + n2) * 16 + l15;
            float v0 = acc[rg][n2][0], v1 = acc[rg][n2][1], v2 = acc[rg][n2][2], v3 = acc[rg][n2][3];
            unsigned h0 = rne_hi(v0), h1 = rne_hi(v1), h2 = rne_hi(v2), h3 = rne_hi(v3);
            ushort4 ph, pl;
            ph.x = (ushort)h0; ph.y = (ushort)h1; ph.z = (ushort)h2; ph.w = (ushort)h3;
            pl.x = (ushort)rne_hi(v0 - bf16val(h0));
            pl.y = (ushort)rne_hi(v1 - bf16val(h1));
            pl.z = (ushort)rne_hi(v2 - bf16val(h2));
            pl.w = (ushort)rne_hi(v3 - bf16val(h3));
            size_t o = ((size_t)(bb * H + c) << 10) + nIdx;
            *(ushort4*)&hth[o] = ph;
            *(ushort4*)&htl[o] = pl;
        }
    }
    // ---- s1/s2 (exact x.wa) from wave 0 of chalf==0 blocks ----
    if (chalf == 0 && w == 0) {
        sp1a += __shfl_xor(sp1a, 16); sp1a += __shfl_xor(sp1a, 32);
        sp2a += __shfl_xor(sp2a, 16); sp2a += __shfl_xor(sp2a, 32);
        sp1b += __shfl_xor(sp1b, 16); sp1b += __shfl_xor(sp1b, 32);
        sp2b += __shfl_xor(sp2b, 16); sp2b += __shfl_xor(sp2b, 32);
        if (quad == 0) {
            s1[row0 + l15] = sp1a; s2[row0 + l15] = sp2a;
            s1[row0 + 16 + l15] = sp1b; s2[row0 + 16 + l15] = sp2b;
        }
        float m = fmaxf(sp2a, sp2b);
#pragma unroll
        for (int off = 1; off <= 8; off <<= 1) m = fmaxf(m, __shfl_xor(m, off));
        if (lane == 0) {
            unsigned bt = __float_as_uint(m);
            unsigned keyv = (bt & 0x80000000u) ? ~bt : (bt | 0x80000000u);
            atomicMax(&s2maxkey[bb], keyv);
        }
    }
}

// ---------------------------------------------------------------------------
// GAT: out = relu((P/l) @ (h_hi+h_lo)). 256 thr, 64 i x 128 c; h-tile dbuf,
// one barrier per jt; mask/s2 prefetched 2 ahead; all 4 waves gen P.
template <int LAST>
__global__ __launch_bounds__(256, 2) void k_gat(const ushort* __restrict__ hth, const ushort* __restrict__ htl,
                                                const float* __restrict__ s1, const float* __restrict__ s2,
                                                const unsigned* __restrict__ mask32,
                                                const unsigned* __restrict__ s2maxkey,
                                                float* __restrict__ outf,
                                                ushort* __restrict__ oxhi, ushort* __restrict__ oxlo,
                                                float* __restrict__ psum, float* __restrict__ pmax) {
    __shared__ __align__(16) ushort tile[2][8192];  // e=[hilo*8+n][quad][l15][8us]
    __shared__ __align__(16) ushort p_s[2][2048];   // [rg][quad][l15][8us]
    __shared__ float l_s[64];
    const int lin = blockIdx.x;                     // 512 blocks
    const int xcd = lin & 7, sl = lin >> 3;
    const int b = xcd * 2 + (sl & 1);               // batch pinned to XCD pair
    const int chunk = (sl >> 1) & 15;
    const int chalf = sl >> 5;
    const int i0 = chunk * 64;
    const int t = threadIdx.x;
    const int lane = t & 63, w = t >> 6;            // wave w owns P rows rg=w
    const int l15 = lane & 15, quad = lane >> 4;
    const int nb = 2 * w;
    const int fo = quad * 128 + l15 * 8;

    unsigned key = s2maxkey[b];
    unsigned mb = (key & 0x80000000u) ? (key ^ 0x80000000u) : ~key;
    const float s2max = __uint_as_float(mb);

    const int i = i0 + w * 16 + l15;
    const float s1v = s1[b * N + i];
    const float tmx = s1v + s2max;
    const float mrow = fmaxf(tmx, ALPHA * tmx);
    const unsigned* mp = mask32 + (size_t)(b * N + i) * 32;
    const float* s2b = s2 + b * N;

    const ushort* hbh = hth + ((size_t)(b * H + chalf * 128) << 10);
    const ushort* hbl = htl + ((size_t)(b * H + chalf * 128) << 10);
    const ushort* srcb[4];
#pragma unroll
    for (int i2 = 0; i2 < 4; i2++) {
        int e = w * 4 + i2;
        const ushort* sb = (e < 8) ? hbh : hbl;
        int n = e & 7;
        srcb[i2] = sb + (((size_t)(n * 16 + l15)) << 10) + quad * 8;
    }

    floatx4 acc[4][2];
    floatx4 z = {0.f, 0.f, 0.f, 0.f};
#pragma unroll
    for (int rg = 0; rg < 4; rg++) { acc[rg][0] = z; acc[rg][1] = z; }
    float lacc = 0.f;

    auto pgen = [&](unsigned mw, float4 sa, float4 sbv, int buf) {
        const unsigned mbyte = (mw >> (quad * 8)) & 0xffu;
        float sv[8] = {sa.x, sa.y, sa.z, sa.w, sbv.x, sbv.y, sbv.z, sbv.w};
        short8 A;
        float ls = 0.f;
#pragma unroll
        for (int j = 0; j < 8; j++) {
            float e1 = s1v + sv[j];
            e1 = fmaxf(e1, ALPHA * e1);
            float p = __expf(e1 - mrow);
            p = ((mbyte >> j) & 1u) ? p : 0.f;
            unsigned hi = rne_hi(p);
            ls += bf16val(hi);
            A[j] = (short)hi;
        }
        ls += __shfl_xor(ls, 16);
        ls += __shfl_xor(ls, 32);
        lacc += ls;
        *(short8*)&p_s[buf][w * 512 + fo] = A;
    };

    // prologue: stage tile[0] + P[0]; prefetch jt=1 operands
#pragma unroll
    for (int i2 = 0; i2 < 4; i2++) ASYNC16(srcb[i2], &tile[0][(w * 4 + i2) * 512]);
    {
        unsigned mw0 = mp[0];
        float4 sa0 = *(const float4*)(s2b + quad * 8);
        float4 sb0 = *(const float4*)(s2b + quad * 8 + 4);
        pgen(mw0, sa0, sb0, 0);
    }
    unsigned mw_n = mp[1];
    float4 sa_n = *(const float4*)(s2b + 32 + quad * 8);
    float4 sb_n = *(const float4*)(s2b + 32 + quad * 8 + 4);
    __syncthreads();

#pragma unroll 2
    for (int jt = 0; jt < 32; jt++) {
        const int cur = jt & 1, nxt = cur ^ 1;
        if (jt < 31) {
            const int j0n = (jt + 1) * 32;
#pragma unroll
            for (int i2 = 0; i2 < 4; i2++) ASYNC16(srcb[i2] + j0n, &tile[nxt][(w * 4 + i2) * 512]);
        }
        short8 Ap[4];
#pragma unroll
        for (int rg = 0; rg < 4; rg++) Ap[rg] = *(const short8*)&p_s[cur][rg * 512 + fo];
        short8 Bh0 = *(const short8*)&tile[cur][nb * 512 + fo];
        short8 Bh1 = *(const short8*)&tile[cur][(nb + 1) * 512 + fo];
        short8 Bl0 = *(const short8*)&tile[cur][(8 + nb) * 512 + fo];
        short8 Bl1 = *(const short8*)&tile[cur][(8 + nb + 1) * 512 + fo];
#pragma unroll
        for (int rg = 0; rg < 4; rg++) {
            acc[rg][0] = mfma16(Ap[rg], Bh0, acc[rg][0]);
            acc[rg][0] = mfma16(Ap[rg], Bl0, acc[rg][0]);
            acc[rg][1] = mfma16(Ap[rg], Bh1, acc[rg][1]);
            acc[rg][1] = mfma16(Ap[rg], Bl1, acc[rg][1]);
        }
        if (jt < 31) {
            pgen(mw_n, sa_n, sb_n, nxt);
            const int jp = (jt + 2 <= 31) ? jt + 2 : 31;
            mw_n = mp[jp];
            sa_n = *(const float4*)(s2b + jp * 32 + quad * 8);
            sb_n = *(const float4*)(s2b + jp * 32 + quad * 8 + 4);
        }
        __syncthreads();
    }
    if (quad == 0) l_s[w * 16 + l15] = lacc;
    __syncthreads();

    float inv[4][4];
#pragma unroll
    for (int rg = 0; rg < 4; rg++)
#pragma unroll
        for (int r = 0; r < 4; r++) inv[rg][r] = 1.f / l_s[rg * 16 + quad * 4 + r];

    const size_t rbase = (size_t)b * N + i0;
    float colsum[2] = {0.f, 0.f}, colmax[2] = {-INFINITY, -INFINITY};
#pragma unroll
    for (int rg = 0; rg < 4; rg++)
#pragma unroll
        for (int n2 = 0; n2 < 2; n2++) {
            const int c = chalf * 128 + (nb + n2) * 16 + l15;
#pragma unroll
            for (int r = 0; r < 4; r++) {
                float v = fmaxf(acc[rg][n2][r] * inv[rg][r], 0.f);
                const size_t row = rbase + rg * 16 + quad * 4 + r;
                if (LAST) {
                    outf[row * H + c] = v;
                    colsum[n2] += v;
                    colmax[n2] = fmaxf(colmax[n2], v);
                } else {
                    unsigned hi = rne_hi(v);
                    oxhi[row * H + c] = (ushort)hi;
                    oxlo[row * H + c] = (ushort)rne_hi(v - bf16val(hi));
                }
            }
        }
    if (LAST) {
#pragma unroll
        for (int n2 = 0; n2 < 2; n2++) {
            float s = colsum[n2], m = colmax[n2];
            s += __shfl_xor(s, 16); s += __shfl_xor(s, 32);
            m = fmaxf(m, __shfl_xor(m, 16)); m = fmaxf(m, __shfl_xor(m, 32));
            if (quad == 0) {
                const int c = chalf * 128 + (nb + n2) * 16 + l15;
                psum[(b * 16 + chunk) * H + c] = s;
                pmax[(b * 16 + chunk) * H + c] = m;
            }
        }
    }
}

// ---------------------------------------------------------------------------
// finish mean+max over 16 chunk-partials, then 2-layer MLP -> g[b,:]
__global__ __launch_bounds__(256) void k_pool2(const float* __restrict__ psum,
                                               const float* __restrict__ pmax,
                                               const float* __restrict__ W1, const float* __restrict__ b1,
                                               const float* __restrict__ W2, const float* __restrict__ b2,
                                               float* __restrict__ gout) {
    __shared__ float g_s[H];
    __shared__ float t_s[H];
    const int b = blockIdx.x;
    const int c = threadIdx.x;
    float s = 0.f, m = -INFINITY;
#pragma unroll
    for (int ch = 0; ch < 16; ch++) {
        s += psum[(b * 16 + ch) * H + c];
        m = fmaxf(m, pmax[(b * 16 + ch) * H + c]);
    }
    g_s[c] = s * (1.f / N) + m;
    __syncthreads();
    float a = b1[c];
    for (int k = 0; k < H; k++) a += g_s[k] * W1[k * H + c];
    t_s[c] = fmaxf(a, 0.f);
    __syncthreads();
    float o = b2[c];
    for (int k = 0; k < H; k++) o += t_s[k] * W2[k * H + c];
    gout[b * H + c] = o;
}

// ---------------------------------------------------------------------------
extern "C" void kernel_launch(void* const* d_in, const int* in_sizes, int n_in,
                              void* d_out, int out_size, void* d_ws, size_t ws_size,
                              hipStream_t stream) {
    const float* nf    = (const float*)d_in[0];
    const float* adj   = (const float*)d_in[1];
    const float* emb_W = (const float*)d_in[2];
    const float* emb_b = (const float*)d_in[3];
    const float* W0    = (const float*)d_in[4];
    const float* a1_0  = (const float*)d_in[5];
    const float* a2_0  = (const float*)d_in[6];
    const float* W1    = (const float*)d_in[7];
    const float* a1_1  = (const float*)d_in[8];
    const float* a2_1  = (const float*)d_in[9];
    const float* gpW1  = (const float*)d_in[10];
    const float* gpb1  = (const float*)d_in[11];
    const float* gpW2  = (const float*)d_in[12];
    const float* gpb2  = (const float*)d_in[13];

    float* xout = (float*)d_out;
    float* gout = xout + B * N * H;

    char* w = (char*)d_ws;
    ushort* xhi      = (ushort*)(w);
    ushort* xlo      = (ushort*)(w + 8388608);
    ushort* hth      = (ushort*)(w + 16777216);
    ushort* htl      = (ushort*)(w + 25165824);
    unsigned* mask32 = (unsigned*)(w + 33554432);
    float* s1        = (float*)(w + 35651584);
    float* s2        = (float*)(w + 35717120);
    ushort* wth      = (ushort*)(w + 35782656);
    ushort* wtl      = (ushort*)(w + 36044800);
    float* wa1       = (float*)(w + 36306944);
    float* wa2       = (float*)(w + 36308992);
    unsigned* keys   = (unsigned*)(w + 36311040);
    // psum/pmax overlay xhi (dead after gemm<1>; written by gat<1>)
    float* psum      = (float*)(w);
    float* pmax      = (float*)(w + 262144);

    hipMemsetAsync(keys, 0, 128, stream);
    k_mask<<<1024, 256, 0, stream>>>(adj, mask32);
    k_prep<<<34, 256, 0, stream>>>(W0, W1, a1_0, a2_0, a1_1, a2_1, wth, wtl, wa1, wa2);
    k_embed<<<B * N / EMB_ROWS, 256, 0, stream>>>(nf, emb_W, emb_b, xhi, xlo);

    // layer 0
    k_gemm<<<B * N / 32 * 2, 256, 0, stream>>>(xhi, xlo, wth, wtl, wa1, wa2,
                                               hth, htl, s1, s2, keys);
    k_gat<0><<<512, 256, 0, stream>>>(hth, htl, s1, s2, mask32, keys,
                                      nullptr, xhi, xlo, nullptr, nullptr);

    // layer 1
    k_gemm<<<B * N / 32 * 2, 256, 0, stream>>>(xhi, xlo, wth + H * H, wtl + H * H, wa1 + H, wa2 + H,
                                               hth, htl, s1, s2, keys + 16);
    k_gat<1><<<512, 256, 0, stream>>>(hth, htl, s1, s2, mask32, keys + 16,
                                      xout, nullptr, nullptr, psum, pmax);

    // pooling MLP
    k_pool2<<<B, 256, 0, stream>>>(psum, pmax, gpW1, gpb1, gpW2, gpb2, gout);
}